// Round 16
// baseline (92.243 us; speedup 1.0000x reference)
//
#include <hip/hip_runtime.h>
#include <hip/hip_bf16.h>

#define BSZ 8
#define T 2048
#define C 1024
#define H 64
#define M (BSZ*T)

typedef __attribute__((ext_vector_type(4))) float f32x4;
typedef __attribute__((ext_vector_type(8))) short bf16x8;
typedef __attribute__((ext_vector_type(4))) short s16x4;
typedef __attribute__((ext_vector_type(8))) short s16x8;

static __device__ __forceinline__ short f2bf(float f) {
  union { float f; unsigned u; } c; c.f = f;
  unsigned u = c.u;
  u = (u + 0x7fffu + ((u >> 16) & 1u)) >> 16;   // RNE, finite inputs only
  return (short)u;
}

// ---------------- Kernel 0: wt[w][h][c] (bf16) = W_w[c][h] ----------------
__global__ __launch_bounds__(256) void k_wt(const float* __restrict__ Wq,
                                            const float* __restrict__ Wk,
                                            const float* __restrict__ Wv,
                                            short* __restrict__ wt) {
  int idx = blockIdx.x * 256 + threadIdx.x;  // [0, 3*H*C)
  int c = idx & (C - 1);
  int n = idx >> 10;           // w*H + h
  int w = n >> 6;
  int h = n & (H - 1);
  const float* W = (w == 0) ? Wq : (w == 1) ? Wk : Wv;
  wt[idx] = f2bf(W[c * H + h]);
}

// ---------------- Kernel 1: fused QKV projection ---------------------------
// x: r7's coalesced LDS pipeline, 2 chunks ahead (HBM stream — must stay
// coalesced, r13 lesson). W: NO LDS — B-fragments loaded per-lane straight
// from L2 (384KB, resident) into 2 register sets, reloaded one full chunk
// before consumption (r13's half-chunk refill was the other failure mode).
// Accumulation order identical to r7 -> bit-identical output. Barriers only
// protect the 8KB xs buffers now.
__global__ __launch_bounds__(256) void k_qkv(const float* __restrict__ x,
                                             const short* __restrict__ wt,
                                             short* __restrict__ qb,
                                             short* __restrict__ kb,
                                             short* __restrict__ vt) {
  __shared__ short xs[2][32 * 64];
  const int tid = threadIdx.x;
  const int m0 = blockIdx.x * 32;
  const int lane = tid & 63;
  const int wid = tid >> 6;             // 0..3
  const int g16 = lane >> 4, l16 = lane & 15;
  const int row0 = (wid & 1) * 16;      // wave's 16 rows
  const int nc0 = (wid >> 1) * 96;      // wave's 96 output cols

  f32x4 acc[6];
  #pragma unroll
  for (int i = 0; i < 6; ++i) acc[i] = (f32x4){0.f, 0.f, 0.f, 0.f};

  const int xr = tid >> 4;              // 0..15
  const int xc4 = (tid & 15) * 4;
  const int xsw = xc4 ^ ((xr & 7) << 3);
  const int fsw = (l16 & 7) << 3;

  float4 xA0, xA1, xB0, xB1;
  // W fragment sets: w{S}{ks}{nt}, 12 s16x8 per set
  s16x8 wA00, wA01, wA02, wA03, wA04, wA05;
  s16x8 wA10, wA11, wA12, wA13, wA14, wA15;
  s16x8 wB00, wB01, wB02, wB03, wB04, wB05;
  s16x8 wB10, wB11, wB12, wB13, wB14, wB15;

  const short* wbase = &wt[(size_t)(nc0 + l16) * C + g16 * 8];

#define XLOAD(S, kc) do { \
    x##S##0 = *(const float4*)&x[(size_t)(m0 + xr) * C + (kc) + xc4]; \
    x##S##1 = *(const float4*)&x[(size_t)(m0 + xr + 16) * C + (kc) + xc4]; \
  } while (0)

#define XSTORE(S, buf) do { \
    s16x4 h0 = { f2bf((x##S##0).x), f2bf((x##S##0).y), f2bf((x##S##0).z), f2bf((x##S##0).w) }; \
    s16x4 h1 = { f2bf((x##S##1).x), f2bf((x##S##1).y), f2bf((x##S##1).z), f2bf((x##S##1).w) }; \
    *(s16x4*)&xs[buf][xr * 64 + xsw] = h0; \
    *(s16x4*)&xs[buf][(xr + 16) * 64 + xsw] = h1; \
  } while (0)

#define WFRAG(S, kc) do { \
    const short* wb = wbase + (kc); \
    w##S##00 = *(const s16x8*)(wb +  0 * 16 * C); \
    w##S##01 = *(const s16x8*)(wb +  1 * 16 * C); \
    w##S##02 = *(const s16x8*)(wb +  2 * 16 * C); \
    w##S##03 = *(const s16x8*)(wb +  3 * 16 * C); \
    w##S##04 = *(const s16x8*)(wb +  4 * 16 * C); \
    w##S##05 = *(const s16x8*)(wb +  5 * 16 * C); \
    w##S##10 = *(const s16x8*)(wb +  0 * 16 * C + 32); \
    w##S##11 = *(const s16x8*)(wb +  1 * 16 * C + 32); \
    w##S##12 = *(const s16x8*)(wb +  2 * 16 * C + 32); \
    w##S##13 = *(const s16x8*)(wb +  3 * 16 * C + 32); \
    w##S##14 = *(const s16x8*)(wb +  4 * 16 * C + 32); \
    w##S##15 = *(const s16x8*)(wb +  5 * 16 * C + 32); \
  } while (0)

#define COMPUTE_W(buf, S) do { \
    { \
      bf16x8 a = *(const bf16x8*)&xs[buf][(row0 + l16) * 64 + ((g16 * 8) ^ fsw)]; \
      acc[0] = __builtin_amdgcn_mfma_f32_16x16x32_bf16(a, w##S##00, acc[0], 0, 0, 0); \
      acc[1] = __builtin_amdgcn_mfma_f32_16x16x32_bf16(a, w##S##01, acc[1], 0, 0, 0); \
      acc[2] = __builtin_amdgcn_mfma_f32_16x16x32_bf16(a, w##S##02, acc[2], 0, 0, 0); \
      acc[3] = __builtin_amdgcn_mfma_f32_16x16x32_bf16(a, w##S##03, acc[3], 0, 0, 0); \
      acc[4] = __builtin_amdgcn_mfma_f32_16x16x32_bf16(a, w##S##04, acc[4], 0, 0, 0); \
      acc[5] = __builtin_amdgcn_mfma_f32_16x16x32_bf16(a, w##S##05, acc[5], 0, 0, 0); \
    } \
    { \
      bf16x8 a = *(const bf16x8*)&xs[buf][(row0 + l16) * 64 + ((32 + g16 * 8) ^ fsw)]; \
      acc[0] = __builtin_amdgcn_mfma_f32_16x16x32_bf16(a, w##S##10, acc[0], 0, 0, 0); \
      acc[1] = __builtin_amdgcn_mfma_f32_16x16x32_bf16(a, w##S##11, acc[1], 0, 0, 0); \
      acc[2] = __builtin_amdgcn_mfma_f32_16x16x32_bf16(a, w##S##12, acc[2], 0, 0, 0); \
      acc[3] = __builtin_amdgcn_mfma_f32_16x16x32_bf16(a, w##S##13, acc[3], 0, 0, 0); \
      acc[4] = __builtin_amdgcn_mfma_f32_16x16x32_bf16(a, w##S##14, acc[4], 0, 0, 0); \
      acc[5] = __builtin_amdgcn_mfma_f32_16x16x32_bf16(a, w##S##15, acc[5], 0, 0, 0); \
    } \
  } while (0)

  XLOAD(A, 0);
  XSTORE(A, 0);          // waits on A x-loads (first tile, unavoidable)
  XLOAD(B, 64);          // in flight across the barrier
  WFRAG(A, 0);           // W for chunk 0 (L2)
  WFRAG(B, 64);          // W for chunk 1
  __syncthreads();

  #pragma unroll 1
  for (int ii = 0; ii < 8; ++ii) {
    // chunk 2ii: xs buf0, W set A
    if (ii < 7) XLOAD(A, (2 * ii + 2) * 64);
    XSTORE(B, 1);
    COMPUTE_W(0, A);
    __syncthreads();
    // chunk 2ii+1: xs buf1, W set B
    if (ii < 7) {
      XLOAD(B, (2 * ii + 3) * 64);
      XSTORE(A, 0);
      WFRAG(A, (2 * ii + 2) * 64);   // set A free (consumed above); 1 chunk ahead
    }
    COMPUTE_W(1, B);
    if (ii < 7) {
      __syncthreads();
      WFRAG(B, (2 * ii + 3) * 64);   // set B free; lands during next half-iter
    }
  }
#undef XLOAD
#undef XSTORE
#undef WFRAG
#undef COMPUTE_W

  const int r0 = row0 + g16 * 4;
  #pragma unroll
  for (int nt = 0; nt < 6; ++nt) {
    const int nglob = nc0 + nt * 16;
    const int which = nglob >> 6;            // 0=q 1=k 2=v
    const int col = (nglob & 63) + l16;
    #pragma unroll
    for (int j = 0; j < 4; ++j) {
      const int tg = m0 + r0 + j;
      const short val = f2bf(acc[nt][j]);
      if (which == 0)      qb[tg * H + col] = val;
      else if (which == 1) kb[tg * H + col] = val;
      else {
        const int b = tg >> 11, tl = tg & (T - 1);
        vt[((b << 6) + col) * T + tl] = val;
      }
    }
  }
}

// ---------------- Kernel 2: flash attention, causal pair-tiling (FROZEN) ---
// Block = q-tile pair (t, 127-t): total KV iters == 65 for every pair.
// GRID MUST BE BSZ*T/32 = 512. Swapped-operand MFMA + defer-max. LDS
// overlay: plds aliases Ow. launch_bounds(512,4); (512,8) spills.
__global__ __launch_bounds__(512, 4) void k_attn(const short* __restrict__ qb,
                                                 const short* __restrict__ kb,
                                                 const short* __restrict__ vt,
                                                 const float* __restrict__ cvp,
                                                 float* __restrict__ out) {
  __shared__ __align__(16) char smem[34816];
  short (*plds)[2][16][40] = (short (*)[2][16][40])smem;   // 20480 B (loop)
  float (*Ow)[16][68]      = (float (*)[16][68])smem;      // 34816 B (merge)
  __shared__ float mw[8][16];
  __shared__ float Lw[8][16];
  const int pid = blockIdx.x;
  const int b = pid & 7;                  // batch->XCD affinity (L2 locality)
  const int pr = pid >> 3;                // 0..63
  const int tA = pr, tB = 127 - pr;
  const int q0A = tA << 4, q0B = tB << 4;
  const int nitA = (q0A + 47) >> 5;       // ceil((q0+16)/32)
  const int nitB = (q0B + 47) >> 5;
  const int NT = nitA + nitB;             // == 65 for all pairs
  int wA = (8 * nitA + (NT >> 1)) / NT;   // waves for tile A, proportional
  wA = wA < 1 ? 1 : (wA > 7 ? 7 : wA);

  const int tid = threadIdx.x;
  const int wid = tid >> 6;               // 0..7
  const int lane = tid & 63;
  const int g16 = lane >> 4, l16 = lane & 15;
  const float cv = cvp[0];
  const float SCL = 0.125f * 1.44269504f; // 1/sqrt(64) * log2(e)

  const bool onA = (wid < wA);
  const int q0 = onA ? q0A : q0B;
  const int nitW = onA ? nitA : nitB;
  const int nwt = onA ? wA : 8 - wA;
  const int wg = onA ? wid : wid - wA;
  const int npw = (nitW + nwt - 1) / nwt;
  const int lo = wg * npw;
  const int hi = (lo + npw < nitW) ? lo + npw : nitW;

  const short* qp = qb + ((size_t)(b << 11) + q0 + l16) * H + g16 * 8;
  bf16x8 qf0 = *(const bf16x8*)qp;
  bf16x8 qf1 = *(const bf16x8*)(qp + 32);
  const int qg = q0 + l16;

  float m = -3e38f, L = 0.f;              // per-lane partials
  f32x4 O[4];
  #pragma unroll
  for (int t4 = 0; t4 < 4; ++t4) O[t4] = (f32x4){0.f, 0.f, 0.f, 0.f};

  if (lo < hi) {
    const short* kp = kb + ((size_t)(b << 11) + lo * 32 + l16) * H + g16 * 8;
    const short* vp = vt + ((size_t)(b << 6) + l16) * T + lo * 32 + g16 * 8;
    bf16x8 kc0 = *(const bf16x8*)kp;
    bf16x8 kc1 = *(const bf16x8*)(kp + 32);
    bf16x8 kc2 = *(const bf16x8*)(kp + 16 * H);
    bf16x8 kc3 = *(const bf16x8*)(kp + 16 * H + 32);
    kp += 32 * H;

    for (int it = lo; it < hi; ++it) {
      bf16x8 kn0, kn1, kn2, kn3;
      const bool more = (it + 1 < hi);
      if (more) {                         // prefetch next K tile
        kn0 = *(const bf16x8*)kp;
        kn1 = *(const bf16x8*)(kp + 32);
        kn2 = *(const bf16x8*)(kp + 16 * H);
        kn3 = *(const bf16x8*)(kp + 16 * H + 32);
      }
      // V for current iter, issued before softmax
      bf16x8 v0 = *(const bf16x8*)vp;
      bf16x8 v1 = *(const bf16x8*)(vp + 16 * T);
      bf16x8 v2 = *(const bf16x8*)(vp + 32 * T);
      bf16x8 v3 = *(const bf16x8*)(vp + 48 * T);

      f32x4 s0 = {0.f,0.f,0.f,0.f}, s1 = {0.f,0.f,0.f,0.f};
      s0 = __builtin_amdgcn_mfma_f32_16x16x32_bf16(kc0, qf0, s0, 0, 0, 0);
      s0 = __builtin_amdgcn_mfma_f32_16x16x32_bf16(kc1, qf1, s0, 0, 0, 0);
      s1 = __builtin_amdgcn_mfma_f32_16x16x32_bf16(kc2, qf0, s1, 0, 0, 0);
      s1 = __builtin_amdgcn_mfma_f32_16x16x32_bf16(kc3, qf1, s1, 0, 0, 0);

      const int kv0 = it << 5;
      const int kvb = kv0 + g16 * 4;
      const bool diag = (kv0 + 31 > q0);  // tile straddles the causal edge
      float sv[8];
      if (diag) {
        #pragma unroll
        for (int r = 0; r < 8; ++r) {
          const int kvg = kvb + ((r >> 2) << 4) + (r & 3);
          const float s = ((r < 4) ? s0[r] : s1[r - 4]) * SCL;
          sv[r] = (kvg <= qg) ? s : -1e30f;
        }
      } else {
        #pragma unroll
        for (int r = 0; r < 8; ++r)
          sv[r] = ((r < 4) ? s0[r] : s1[r - 4]) * SCL;
      }

      float pmax = fmaxf(fmaxf(fmaxf(sv[0], sv[1]), fmaxf(sv[2], sv[3])),
                         fmaxf(fmaxf(sv[4], sv[5]), fmaxf(sv[6], sv[7])));
      if (!__all(pmax <= m + 7.f)) {      // slow path: true max + rescale
        float v = pmax;
        v = fmaxf(v, __shfl_xor(v, 16, 64));
        v = fmaxf(v, __shfl_xor(v, 32, 64));
        const float mn = fmaxf(m, v);
        const float al = exp2f(m - mn);
        m = mn;
        L *= al;
        #pragma unroll
        for (int t4 = 0; t4 < 4; ++t4) O[t4] *= al;
      }

      float p[8];
      #pragma unroll
      for (int r = 0; r < 8; ++r) {
        const int kvg = kvb + ((r >> 2) << 4) + (r & 3);
        const float sp = fminf(fmaxf((float)(kvg + 1) * (1.f / 2048.f) + cv, 0.f), 1.f);
        p[r] = exp2f(sv[r] - m) * sp;
      }
      if (diag) {                         // re-mask (guards all-masked rows)
        #pragma unroll
        for (int r = 0; r < 8; ++r) {
          const int kvg = kvb + ((r >> 2) << 4) + (r & 3);
          p[r] = (kvg <= qg) ? p[r] : 0.f;
        }
      }
      L += ((p[0] + p[1]) + (p[2] + p[3])) + ((p[4] + p[5]) + (p[6] + p[7]));

      short (*pl)[40] = plds[wid][it & 1];
      #pragma unroll
      for (int r = 0; r < 8; r += 2) {
        union { float f; unsigned u; } a0, a1;
        a0.f = p[r]; a1.f = p[r + 1];
        const unsigned pk = (a0.u >> 16) | (a1.u & 0xffff0000u);
        *(unsigned*)&pl[l16][((r >> 2) << 4) + g16 * 4 + (r & 3)] = pk;
      }
      bf16x8 pa = *(const bf16x8*)&pl[l16][g16 * 8];
      O[0] = __builtin_amdgcn_mfma_f32_16x16x32_bf16(v0, pa, O[0], 0, 0, 0);
      O[1] = __builtin_amdgcn_mfma_f32_16x16x32_bf16(v1, pa, O[1], 0, 0, 0);
      O[2] = __builtin_amdgcn_mfma_f32_16x16x32_bf16(v2, pa, O[2], 0, 0, 0);
      O[3] = __builtin_amdgcn_mfma_f32_16x16x32_bf16(v3, pa, O[3], 0, 0, 0);

      if (more) { kc0 = kn0; kc1 = kn1; kc2 = kn2; kc3 = kn3; }
      kp += 32 * H;
      vp += 32;
    }
  }

  // ---- phase switch: everyone done reading plds before Ow overwrites it ----
  __syncthreads();

  float Lr = L;
  Lr += __shfl_xor(Lr, 16, 64);
  Lr += __shfl_xor(Lr, 32, 64);
  if (g16 == 0) { mw[wid][l16] = m; Lw[wid][l16] = Lr; }
  #pragma unroll
  for (int t4 = 0; t4 < 4; ++t4)
    *(f32x4*)&Ow[wid][l16][t4 * 16 + g16 * 4] = O[t4];
  __syncthreads();

  // ---- merge: 32 rows (16 tile-A from waves [0,wA), 16 tile-B from
  // waves [wA,8)), thread -> (row, 4 cols) ----
  {
    const int r32 = tid >> 4;             // 0..31
    const int c4 = (tid & 15) << 2;
    const bool rowA = (r32 < 16);
    const int r = rowA ? r32 : r32 - 16;
    const int w0 = rowA ? 0 : wA;
    const int w1 = rowA ? wA : 8;
    const int q0r = rowA ? q0A : q0B;
    float Mx = -3e38f;
    for (int w = w0; w < w1; ++w) Mx = fmaxf(Mx, mw[w][r]);
    float Ls = 0.f;
    f32x4 o = (f32x4){0.f, 0.f, 0.f, 0.f};
    for (int w = w0; w < w1; ++w) {
      const float fw = exp2f(mw[w][r] - Mx);
      Ls += Lw[w][r] * fw;
      f32x4 ow = *(const f32x4*)&Ow[w][r][c4];
      o += ow * fw;
    }
    o *= 1.f / (Ls + 1e-30f);
    *(f32x4*)&out[(size_t)((b << 11) + q0r + r) * H + c4] = o;
  }
}

extern "C" void kernel_launch(void* const* d_in, const int* in_sizes, int n_in,
                              void* d_out, int out_size, void* d_ws, size_t ws_size,
                              hipStream_t stream) {
  const float* x  = (const float*)d_in[0];
  const float* Wq = (const float*)d_in[1];
  const float* Wk = (const float*)d_in[2];
  const float* Wv = (const float*)d_in[3];
  const float* cv = (const float*)d_in[4];
  float* out = (float*)d_out;

  char* ws = (char*)d_ws;
  short* qb = (short*)(ws);                              // 2 MB
  short* kb = (short*)(ws + (size_t)M * H * 2);          // 2 MB
  short* vt = (short*)(ws + (size_t)2 * M * H * 2);      // 2 MB
  short* wt = (short*)(ws + (size_t)3 * M * H * 2);      // 384 KB

  hipLaunchKernelGGL(k_wt, dim3(3 * H * C / 256), dim3(256), 0, stream, Wq, Wk, Wv, wt);
  hipLaunchKernelGGL(k_qkv, dim3(M / 32), dim3(256), 0, stream, x, wt, qb, kb, vt);
  hipLaunchKernelGGL(k_attn, dim3(BSZ * T / 32), dim3(512), 0, stream, qb, kb, vt, cv, out);
}

// Round 17
// 63.358 us; speedup vs baseline: 1.4559x; 1.4559x over previous
//
#include <hip/hip_runtime.h>
#include <hip/hip_bf16.h>

#define BSZ 8
#define T 2048
#define C 1024
#define H 64
#define M (BSZ*T)

typedef __attribute__((ext_vector_type(4))) float f32x4;
typedef __attribute__((ext_vector_type(8))) short bf16x8;
typedef __attribute__((ext_vector_type(4))) short s16x4;
typedef __attribute__((ext_vector_type(8))) short s16x8;

static __device__ __forceinline__ short f2bf(float f) {
  union { float f; unsigned u; } c; c.f = f;
  unsigned u = c.u;
  u = (u + 0x7fffu + ((u >> 16) & 1u)) >> 16;   // RNE, finite inputs only
  return (short)u;
}

// ---------------- Kernel 0: wt[w][h][c] (bf16) = W_w[c][h] ----------------
__global__ __launch_bounds__(256) void k_wt(const float* __restrict__ Wq,
                                            const float* __restrict__ Wk,
                                            const float* __restrict__ Wv,
                                            short* __restrict__ wt) {
  int idx = blockIdx.x * 256 + threadIdx.x;  // [0, 3*H*C)
  int c = idx & (C - 1);
  int n = idx >> 10;           // w*H + h
  int w = n >> 6;
  int h = n & (H - 1);
  const float* W = (w == 0) ? Wq : (w == 1) ? Wk : Wv;
  wt[idx] = f2bf(W[c * H + h]);
}

// ---------------- Kernel 1: fused QKV projection, 2-deep pipeline ----------
// M-tile 32, 4 waves, LDS-staged both operands (coalesced), loads issued 2
// chunks ahead. MEASURED BEST (~23us). Variants that regressed: r11 DMA
// (shallow prefetch, 41us), r13 no-LDS (uncoalesced W, 68us), r16
// W-to-regs (uncoalesced W even from L2, 56us). LDS staging IS the
// coalescing mechanism for lane-transposed operands — keep it.
__global__ __launch_bounds__(256) void k_qkv(const float* __restrict__ x,
                                             const short* __restrict__ wt,
                                             short* __restrict__ qb,
                                             short* __restrict__ kb,
                                             short* __restrict__ vt) {
  __shared__ short xs[2][32 * 64];
  __shared__ short wl[2][192 * 64];
  const int tid = threadIdx.x;
  const int m0 = blockIdx.x * 32;
  const int lane = tid & 63;
  const int wid = tid >> 6;             // 0..3
  const int g16 = lane >> 4, l16 = lane & 15;
  const int row0 = (wid & 1) * 16;      // wave's 16 rows
  const int nc0 = (wid >> 1) * 96;      // wave's 96 output cols

  f32x4 acc[6];
  #pragma unroll
  for (int i = 0; i < 6; ++i) acc[i] = (f32x4){0.f, 0.f, 0.f, 0.f};

  const int xr = tid >> 4;              // 0..15
  const int xc4 = (tid & 15) * 4;
  const int xsw = xc4 ^ ((xr & 7) << 3);
  const int wr = tid >> 3;              // 0..31
  const int wc8 = (tid & 7) * 8;
  const int wsw = wc8 ^ ((wr & 7) << 3);
  const int fsw = (l16 & 7) << 3;

  float4 xA0, xA1, xB0, xB1;
  s16x8 wA0, wA1, wA2, wA3, wA4, wA5;
  s16x8 wB0, wB1, wB2, wB3, wB4, wB5;

#define QKV_LOAD(S, kc) do { \
    x##S##0 = *(const float4*)&x[(size_t)(m0 + xr) * C + (kc) + xc4]; \
    x##S##1 = *(const float4*)&x[(size_t)(m0 + xr + 16) * C + (kc) + xc4]; \
    w##S##0 = *(const s16x8*)&wt[(wr +   0) * C + (kc) + wc8]; \
    w##S##1 = *(const s16x8*)&wt[(wr +  32) * C + (kc) + wc8]; \
    w##S##2 = *(const s16x8*)&wt[(wr +  64) * C + (kc) + wc8]; \
    w##S##3 = *(const s16x8*)&wt[(wr +  96) * C + (kc) + wc8]; \
    w##S##4 = *(const s16x8*)&wt[(wr + 128) * C + (kc) + wc8]; \
    w##S##5 = *(const s16x8*)&wt[(wr + 160) * C + (kc) + wc8]; \
  } while (0)

#define QKV_STORE(S, buf) do { \
    s16x4 h0 = { f2bf((x##S##0).x), f2bf((x##S##0).y), f2bf((x##S##0).z), f2bf((x##S##0).w) }; \
    s16x4 h1 = { f2bf((x##S##1).x), f2bf((x##S##1).y), f2bf((x##S##1).z), f2bf((x##S##1).w) }; \
    *(s16x4*)&xs[buf][xr * 64 + xsw] = h0; \
    *(s16x4*)&xs[buf][(xr + 16) * 64 + xsw] = h1; \
    *(s16x8*)&wl[buf][(wr +   0) * 64 + wsw] = w##S##0; \
    *(s16x8*)&wl[buf][(wr +  32) * 64 + wsw] = w##S##1; \
    *(s16x8*)&wl[buf][(wr +  64) * 64 + wsw] = w##S##2; \
    *(s16x8*)&wl[buf][(wr +  96) * 64 + wsw] = w##S##3; \
    *(s16x8*)&wl[buf][(wr + 128) * 64 + wsw] = w##S##4; \
    *(s16x8*)&wl[buf][(wr + 160) * 64 + wsw] = w##S##5; \
  } while (0)

#define QKV_COMPUTE(buf) do { \
    _Pragma("unroll") \
    for (int ks = 0; ks < 2; ++ks) { \
      bf16x8 a = *(const bf16x8*)&xs[buf][(row0 + l16) * 64 + ((ks * 32 + g16 * 8) ^ fsw)]; \
      _Pragma("unroll") \
      for (int nt = 0; nt < 6; ++nt) { \
        bf16x8 bfr = *(const bf16x8*)&wl[buf][(nc0 + nt * 16 + l16) * 64 + ((ks * 32 + g16 * 8) ^ fsw)]; \
        acc[nt] = __builtin_amdgcn_mfma_f32_16x16x32_bf16(a, bfr, acc[nt], 0, 0, 0); \
      } \
    } \
  } while (0)

  QKV_LOAD(A, 0);
  QKV_STORE(A, 0);       // waits on A loads (first tile, unavoidable)
  QKV_LOAD(B, 64);       // in flight across the barrier
  __syncthreads();

  #pragma unroll 1
  for (int ii = 0; ii < 8; ++ii) {
    if (ii < 7) QKV_LOAD(A, (2 * ii + 2) * 64);
    QKV_STORE(B, 1);
    QKV_COMPUTE(0);
    __syncthreads();
    if (ii < 7) {
      QKV_LOAD(B, (2 * ii + 3) * 64);
      QKV_STORE(A, 0);
    }
    QKV_COMPUTE(1);
    if (ii < 7) __syncthreads();
  }
#undef QKV_LOAD
#undef QKV_STORE
#undef QKV_COMPUTE

  const int r0 = row0 + g16 * 4;
  #pragma unroll
  for (int nt = 0; nt < 6; ++nt) {
    const int nglob = nc0 + nt * 16;
    const int which = nglob >> 6;            // 0=q 1=k 2=v
    const int col = (nglob & 63) + l16;
    #pragma unroll
    for (int j = 0; j < 4; ++j) {
      const int tg = m0 + r0 + j;
      const short val = f2bf(acc[nt][j]);
      if (which == 0)      qb[tg * H + col] = val;
      else if (which == 1) kb[tg * H + col] = val;
      else {
        const int b = tg >> 11, tl = tg & (T - 1);
        vt[((b << 6) + col) * T + tl] = val;
      }
    }
  }
}

// ---------------- Kernel 2: flash attention, causal pair-tiling ------------
// Block = q-tile pair (t, 127-t): total KV iters == 65 for every pair, so
// all 512 blocks have equal work. GRID MUST BE BSZ*T/32 = 512 — launching
// 1024 duplicates every pair (benign values, 2x work; r14's 94us bug).
// 8 waves split proportionally (wA = round(8*nitA/65)). Swapped-operand
// MFMA + defer-max. LDS overlay: plds aliases Ow. launch_bounds(512,4):
// (512,8) forced 32-VGPR spills — do not tighten.
__global__ __launch_bounds__(512, 4) void k_attn(const short* __restrict__ qb,
                                                 const short* __restrict__ kb,
                                                 const short* __restrict__ vt,
                                                 const float* __restrict__ cvp,
                                                 float* __restrict__ out) {
  __shared__ __align__(16) char smem[34816];
  short (*plds)[2][16][40] = (short (*)[2][16][40])smem;   // 20480 B (loop)
  float (*Ow)[16][68]      = (float (*)[16][68])smem;      // 34816 B (merge)
  __shared__ float mw[8][16];
  __shared__ float Lw[8][16];
  const int pid = blockIdx.x;
  const int b = pid & 7;                  // batch->XCD affinity (L2 locality)
  const int pr = pid >> 3;                // 0..63
  const int tA = pr, tB = 127 - pr;
  const int q0A = tA << 4, q0B = tB << 4;
  const int nitA = (q0A + 47) >> 5;       // ceil((q0+16)/32)
  const int nitB = (q0B + 47) >> 5;
  const int NT = nitA + nitB;             // == 65 for all pairs
  int wA = (8 * nitA + (NT >> 1)) / NT;   // waves for tile A, proportional
  wA = wA < 1 ? 1 : (wA > 7 ? 7 : wA);

  const int tid = threadIdx.x;
  const int wid = tid >> 6;               // 0..7
  const int lane = tid & 63;
  const int g16 = lane >> 4, l16 = lane & 15;
  const float cv = cvp[0];
  const float SCL = 0.125f * 1.44269504f; // 1/sqrt(64) * log2(e)

  const bool onA = (wid < wA);
  const int q0 = onA ? q0A : q0B;
  const int nitW = onA ? nitA : nitB;
  const int nwt = onA ? wA : 8 - wA;
  const int wg = onA ? wid : wid - wA;
  const int npw = (nitW + nwt - 1) / nwt;
  const int lo = wg * npw;
  const int hi = (lo + npw < nitW) ? lo + npw : nitW;

  const short* qp = qb + ((size_t)(b << 11) + q0 + l16) * H + g16 * 8;
  bf16x8 qf0 = *(const bf16x8*)qp;
  bf16x8 qf1 = *(const bf16x8*)(qp + 32);
  const int qg = q0 + l16;

  float m = -3e38f, L = 0.f;              // per-lane partials
  f32x4 O[4];
  #pragma unroll
  for (int t4 = 0; t4 < 4; ++t4) O[t4] = (f32x4){0.f, 0.f, 0.f, 0.f};

  if (lo < hi) {
    const short* kp = kb + ((size_t)(b << 11) + lo * 32 + l16) * H + g16 * 8;
    const short* vp = vt + ((size_t)(b << 6) + l16) * T + lo * 32 + g16 * 8;
    bf16x8 kc0 = *(const bf16x8*)kp;
    bf16x8 kc1 = *(const bf16x8*)(kp + 32);
    bf16x8 kc2 = *(const bf16x8*)(kp + 16 * H);
    bf16x8 kc3 = *(const bf16x8*)(kp + 16 * H + 32);
    kp += 32 * H;

    for (int it = lo; it < hi; ++it) {
      bf16x8 kn0, kn1, kn2, kn3;
      const bool more = (it + 1 < hi);
      if (more) {                         // prefetch next K tile
        kn0 = *(const bf16x8*)kp;
        kn1 = *(const bf16x8*)(kp + 32);
        kn2 = *(const bf16x8*)(kp + 16 * H);
        kn3 = *(const bf16x8*)(kp + 16 * H + 32);
      }
      // V for current iter, issued before softmax
      bf16x8 v0 = *(const bf16x8*)vp;
      bf16x8 v1 = *(const bf16x8*)(vp + 16 * T);
      bf16x8 v2 = *(const bf16x8*)(vp + 32 * T);
      bf16x8 v3 = *(const bf16x8*)(vp + 48 * T);

      f32x4 s0 = {0.f,0.f,0.f,0.f}, s1 = {0.f,0.f,0.f,0.f};
      s0 = __builtin_amdgcn_mfma_f32_16x16x32_bf16(kc0, qf0, s0, 0, 0, 0);
      s0 = __builtin_amdgcn_mfma_f32_16x16x32_bf16(kc1, qf1, s0, 0, 0, 0);
      s1 = __builtin_amdgcn_mfma_f32_16x16x32_bf16(kc2, qf0, s1, 0, 0, 0);
      s1 = __builtin_amdgcn_mfma_f32_16x16x32_bf16(kc3, qf1, s1, 0, 0, 0);

      const int kv0 = it << 5;
      const int kvb = kv0 + g16 * 4;
      const bool diag = (kv0 + 31 > q0);  // tile straddles the causal edge
      float sv[8];
      if (diag) {
        #pragma unroll
        for (int r = 0; r < 8; ++r) {
          const int kvg = kvb + ((r >> 2) << 4) + (r & 3);
          const float s = ((r < 4) ? s0[r] : s1[r - 4]) * SCL;
          sv[r] = (kvg <= qg) ? s : -1e30f;
        }
      } else {
        #pragma unroll
        for (int r = 0; r < 8; ++r)
          sv[r] = ((r < 4) ? s0[r] : s1[r - 4]) * SCL;
      }

      float pmax = fmaxf(fmaxf(fmaxf(sv[0], sv[1]), fmaxf(sv[2], sv[3])),
                         fmaxf(fmaxf(sv[4], sv[5]), fmaxf(sv[6], sv[7])));
      if (!__all(pmax <= m + 7.f)) {      // slow path: true max + rescale
        float v = pmax;
        v = fmaxf(v, __shfl_xor(v, 16, 64));
        v = fmaxf(v, __shfl_xor(v, 32, 64));
        const float mn = fmaxf(m, v);
        const float al = exp2f(m - mn);
        m = mn;
        L *= al;
        #pragma unroll
        for (int t4 = 0; t4 < 4; ++t4) O[t4] *= al;
      }

      float p[8];
      #pragma unroll
      for (int r = 0; r < 8; ++r) {
        const int kvg = kvb + ((r >> 2) << 4) + (r & 3);
        const float sp = fminf(fmaxf((float)(kvg + 1) * (1.f / 2048.f) + cv, 0.f), 1.f);
        p[r] = exp2f(sv[r] - m) * sp;
      }
      if (diag) {                         // re-mask (guards all-masked rows)
        #pragma unroll
        for (int r = 0; r < 8; ++r) {
          const int kvg = kvb + ((r >> 2) << 4) + (r & 3);
          p[r] = (kvg <= qg) ? p[r] : 0.f;
        }
      }
      L += ((p[0] + p[1]) + (p[2] + p[3])) + ((p[4] + p[5]) + (p[6] + p[7]));

      short (*pl)[40] = plds[wid][it & 1];
      #pragma unroll
      for (int r = 0; r < 8; r += 2) {
        union { float f; unsigned u; } a0, a1;
        a0.f = p[r]; a1.f = p[r + 1];
        const unsigned pk = (a0.u >> 16) | (a1.u & 0xffff0000u);
        *(unsigned*)&pl[l16][((r >> 2) << 4) + g16 * 4 + (r & 3)] = pk;
      }
      bf16x8 pa = *(const bf16x8*)&pl[l16][g16 * 8];
      O[0] = __builtin_amdgcn_mfma_f32_16x16x32_bf16(v0, pa, O[0], 0, 0, 0);
      O[1] = __builtin_amdgcn_mfma_f32_16x16x32_bf16(v1, pa, O[1], 0, 0, 0);
      O[2] = __builtin_amdgcn_mfma_f32_16x16x32_bf16(v2, pa, O[2], 0, 0, 0);
      O[3] = __builtin_amdgcn_mfma_f32_16x16x32_bf16(v3, pa, O[3], 0, 0, 0);

      if (more) { kc0 = kn0; kc1 = kn1; kc2 = kn2; kc3 = kn3; }
      kp += 32 * H;
      vp += 32;
    }
  }

  // ---- phase switch: everyone done reading plds before Ow overwrites it ----
  __syncthreads();

  float Lr = L;
  Lr += __shfl_xor(Lr, 16, 64);
  Lr += __shfl_xor(Lr, 32, 64);
  if (g16 == 0) { mw[wid][l16] = m; Lw[wid][l16] = Lr; }
  #pragma unroll
  for (int t4 = 0; t4 < 4; ++t4)
    *(f32x4*)&Ow[wid][l16][t4 * 16 + g16 * 4] = O[t4];
  __syncthreads();

  // ---- merge: 32 rows (16 tile-A from waves [0,wA), 16 tile-B from
  // waves [wA,8)), thread -> (row, 4 cols) ----
  {
    const int r32 = tid >> 4;             // 0..31
    const int c4 = (tid & 15) << 2;
    const bool rowA = (r32 < 16);
    const int r = rowA ? r32 : r32 - 16;
    const int w0 = rowA ? 0 : wA;
    const int w1 = rowA ? wA : 8;
    const int q0r = rowA ? q0A : q0B;
    float Mx = -3e38f;
    for (int w = w0; w < w1; ++w) Mx = fmaxf(Mx, mw[w][r]);
    float Ls = 0.f;
    f32x4 o = (f32x4){0.f, 0.f, 0.f, 0.f};
    for (int w = w0; w < w1; ++w) {
      const float fw = exp2f(mw[w][r] - Mx);
      Ls += Lw[w][r] * fw;
      f32x4 ow = *(const f32x4*)&Ow[w][r][c4];
      o += ow * fw;
    }
    o *= 1.f / (Ls + 1e-30f);
    *(f32x4*)&out[(size_t)((b << 11) + q0r + r) * H + c4] = o;
  }
}

extern "C" void kernel_launch(void* const* d_in, const int* in_sizes, int n_in,
                              void* d_out, int out_size, void* d_ws, size_t ws_size,
                              hipStream_t stream) {
  const float* x  = (const float*)d_in[0];
  const float* Wq = (const float*)d_in[1];
  const float* Wk = (const float*)d_in[2];
  const float* Wv = (const float*)d_in[3];
  const float* cv = (const float*)d_in[4];
  float* out = (float*)d_out;

  char* ws = (char*)d_ws;
  short* qb = (short*)(ws);                              // 2 MB
  short* kb = (short*)(ws + (size_t)M * H * 2);          // 2 MB
  short* vt = (short*)(ws + (size_t)2 * M * H * 2);      // 2 MB
  short* wt = (short*)(ws + (size_t)3 * M * H * 2);      // 384 KB

  hipLaunchKernelGGL(k_wt, dim3(3 * H * C / 256), dim3(256), 0, stream, Wq, Wk, Wv, wt);
  hipLaunchKernelGGL(k_qkv, dim3(M / 32), dim3(256), 0, stream, x, wt, qb, kb, vt);
  hipLaunchKernelGGL(k_attn, dim3(BSZ * T / 32), dim3(512), 0, stream, qb, kb, vt, cv, out);
}